// Round 1
// baseline (656.095 us; speedup 1.0000x reference)
//
#include <hip/hip_runtime.h>
#include <cstdint>
#include <cstddef>

// ================= bucket-sort CSR build =================
// Buckets of 128 consecutive node ids. Bucket order == node order, so
// bucket_start doubles as the CSR region start and rowptr is
// bucket_start[b] + local exclusive scan. All per-node atomics are LDS-only.
// Bucket edges are packed: src in bits [0,25), local dst in bits [25,32).

#define NODE_SHIFT 7
#define NODE_RANGE 128
#define MAX_B 1024           // supports N <= 131072 (and N < 2^25 for packing)
#define CHUNK 16384          // edges per bcount/bscatter block (64/thread)

typedef short short8 __attribute__((ext_vector_type(8)));
typedef float f32x4 __attribute__((ext_vector_type(4)));

__device__ __forceinline__ unsigned short f2bf(float f) {
    unsigned u = __float_as_uint(f);
    u += 0x7FFFu + ((u >> 16) & 1u);       // round-to-nearest-even
    return (unsigned short)(u >> 16);
}
__device__ __forceinline__ float bf2f(unsigned short h) {
    return __uint_as_float((unsigned)h << 16);
}

__global__ void k_zero(int* __restrict__ p, int n) {
    int i = blockIdx.x * blockDim.x + threadIdx.x;
    if (i < n) p[i] = 0;
}

// per-chunk LDS histogram over buckets; reserve global per-(block,bin) bases
__global__ __launch_bounds__(256) void k_bcount(const int* __restrict__ dst,
                                                int* __restrict__ bucket_cnt,
                                                int* __restrict__ blk_base,
                                                int E, int B) {
    __shared__ int hist[MAX_B];
    int t = threadIdx.x;
    for (int i = t; i < B; i += 256) hist[i] = 0;
    __syncthreads();
    int base = blockIdx.x * CHUNK;
#pragma unroll 8
    for (int j = 0; j < CHUNK / 256; ++j) {
        int e = base + j * 256 + t;
        if (e < E) atomicAdd(&hist[dst[e] >> NODE_SHIFT], 1);
    }
    __syncthreads();
    for (int i = t; i < B; i += 256)
        blk_base[(size_t)blockIdx.x * B + i] = atomicAdd(&bucket_cnt[i], hist[i]);
}

// single-block exclusive scan of bucket counts -> bucket_start[0..B]
__global__ __launch_bounds__(1024) void k_bscan(const int* __restrict__ bucket_cnt,
                                                int* __restrict__ bucket_start,
                                                int* __restrict__ rowptr,
                                                int B, int N) {
    __shared__ int s[1024];
    int t = threadIdx.x;
    int v = (t < B) ? bucket_cnt[t] : 0;
    s[t] = v;
    __syncthreads();
    for (int off = 1; off < 1024; off <<= 1) {
        int add = (t >= off) ? s[t - off] : 0;
        __syncthreads();
        s[t] += add;
        __syncthreads();
    }
    if (t < B) bucket_start[t] = s[t] - v;
    if (t == 1023) {
        bucket_start[B] = s[1023];   // == E
        rowptr[N] = s[1023];
    }
}

// scatter edges into bucket-grouped order via LDS cursors (no global atomics)
__global__ __launch_bounds__(256) void k_bscatter(const int* __restrict__ src,
                                                  const int* __restrict__ dst,
                                                  const int* __restrict__ bucket_start,
                                                  const int* __restrict__ blk_base,
                                                  unsigned* __restrict__ bucket_pk,
                                                  int E, int B) {
    __shared__ int cur[MAX_B];
    int t = threadIdx.x;
    for (int i = t; i < B; i += 256)
        cur[i] = bucket_start[i] + blk_base[(size_t)blockIdx.x * B + i];
    __syncthreads();
    int base = blockIdx.x * CHUNK;
#pragma unroll 8
    for (int j = 0; j < CHUNK / 256; ++j) {
        int e = base + j * 256 + t;
        if (e < E) {
            int d = dst[e];
            int p = atomicAdd(&cur[d >> NODE_SHIFT], 1);
            bucket_pk[p] = (unsigned)src[e] | ((unsigned)(d & (NODE_RANGE - 1)) << 25);
        }
    }
}

// per-bucket: 128-bin LDS histogram -> rowptr/dinv, then local CSR scatter.
__global__ __launch_bounds__(256) void k_bfinal(const unsigned* __restrict__ bucket_pk,
                                                const int* __restrict__ bucket_start,
                                                int* __restrict__ rowptr,
                                                float* __restrict__ dinv,
                                                int* __restrict__ csr_src,
                                                int N) {
    __shared__ int hist[NODE_RANGE];
    __shared__ int sc[NODE_RANGE];
    int t = threadIdx.x;
    int node0 = blockIdx.x * NODE_RANGE;
    int nn = min(NODE_RANGE, N - node0);
    int estart = bucket_start[blockIdx.x];
    int eend   = bucket_start[blockIdx.x + 1];

    if (t < NODE_RANGE) hist[t] = 0;
    __syncthreads();
    for (int e = estart + t; e < eend; e += 256)
        atomicAdd(&hist[bucket_pk[e] >> 25], 1);
    __syncthreads();

    int v = 0;
    if (t < NODE_RANGE) { v = hist[t]; sc[t] = v; }
    __syncthreads();
    for (int off = 1; off < NODE_RANGE; off <<= 1) {
        int add = (t < NODE_RANGE && t >= off) ? sc[t - off] : 0;
        __syncthreads();
        if (t < NODE_RANGE) sc[t] += add;
        __syncthreads();
    }

    int excl = (t < NODE_RANGE) ? (sc[t] - v) : 0;
    if (t < NODE_RANGE) hist[t] = estart + excl;     // becomes the cursor
    if (t < nn) {
        rowptr[node0 + t] = estart + excl;
        dinv[node0 + t] = rsqrtf((float)(v + 1));    // +1 = self-loop
    }
    __syncthreads();

    for (int e = estart + t; e < eend; e += 256) {
        unsigned q = bucket_pk[e];
        int slot = atomicAdd(&hist[q >> 25], 1);
        csr_src[slot] = (int)(q & 0x01FFFFFFu);
    }
}

// ================= GEMM1 via MFMA: h1[N,64] = x[N,512] @ W1[512,64] =========
// bf16 hi/lo split (3 MFMA terms -> ~f32 precision), f32 accumulate.
// Tile 128x64, 256 threads (4 waves), each wave 32 rows x 64 cols:
// 2 m-frags x 4 n-frags of 16x16, K-step 32 (mfma_f32_16x16x32_bf16).

__global__ __launch_bounds__(256) void k_gemm1(const float* __restrict__ x,
                                               const float* __restrict__ W1,
                                               unsigned short* __restrict__ h1,
                                               int N) {
    // stride 40 ushort = 80 B: 8-B aligned rows, 16-B aligned frag reads,
    // bank starts r*20 mod 32 -> 2-way max (free per m136)
    __shared__ unsigned short Ah[128][40];
    __shared__ unsigned short Al[128][40];
    __shared__ unsigned short Bh[64][40];
    __shared__ unsigned short Bl[64][40];

    int t = threadIdx.x;
    int w = t >> 6;
    int l = t & 63;
    int row0 = blockIdx.x * 128;
    int lr = l & 15;            // fragment row (A) / col (B)
    int lk = (l >> 4) * 8;      // fragment k offset

    f32x4 acc[2][4];
#pragma unroll
    for (int mb = 0; mb < 2; ++mb)
#pragma unroll
        for (int nb = 0; nb < 4; ++nb)
            acc[mb][nb] = (f32x4){0.f, 0.f, 0.f, 0.f};

    for (int k0 = 0; k0 < 512; k0 += 32) {
        // ---- stage A tile: 128 rows x 32 k, 4 float4 per thread, coalesced
#pragma unroll
        for (int j = 0; j < 4; ++j) {
            int idx = t + j * 256;          // 0..1023 float4 slots
            int r   = idx >> 3;             // 0..127
            int c4  = idx & 7;              // float4 within 32 cols
            float4 v = {0.f, 0.f, 0.f, 0.f};
            int gr = row0 + r;
            if (gr < N) v = *(const float4*)(x + (size_t)gr * 512 + k0 + c4 * 4);
            ushort4 hi, lo;
            hi.x = f2bf(v.x); lo.x = f2bf(v.x - bf2f(hi.x));
            hi.y = f2bf(v.y); lo.y = f2bf(v.y - bf2f(hi.y));
            hi.z = f2bf(v.z); lo.z = f2bf(v.z - bf2f(hi.z));
            hi.w = f2bf(v.w); lo.w = f2bf(v.w - bf2f(hi.w));
            *(ushort4*)&Ah[r][c4 * 4] = hi;
            *(ushort4*)&Al[r][c4 * 4] = lo;
        }
        // ---- stage B tile transposed: Bt[n][k], 2 float4 per thread
#pragma unroll
        for (int j = 0; j < 2; ++j) {
            int idx = t + j * 256;          // 0..511 float4 slots
            int kk  = idx >> 4;             // 0..31
            int c4  = idx & 15;             // float4 within 64 cols
            float4 v = *(const float4*)(W1 + (size_t)(k0 + kk) * 64 + c4 * 4);
            unsigned short h, lo2;
            h = f2bf(v.x); lo2 = f2bf(v.x - bf2f(h));
            Bh[c4 * 4 + 0][kk] = h; Bl[c4 * 4 + 0][kk] = lo2;
            h = f2bf(v.y); lo2 = f2bf(v.y - bf2f(h));
            Bh[c4 * 4 + 1][kk] = h; Bl[c4 * 4 + 1][kk] = lo2;
            h = f2bf(v.z); lo2 = f2bf(v.z - bf2f(h));
            Bh[c4 * 4 + 2][kk] = h; Bl[c4 * 4 + 2][kk] = lo2;
            h = f2bf(v.w); lo2 = f2bf(v.w - bf2f(h));
            Bh[c4 * 4 + 3][kk] = h; Bl[c4 * 4 + 3][kk] = lo2;
        }
        __syncthreads();

        short8 a0h = *(const short8*)&Ah[w * 32 + lr][lk];
        short8 a0l = *(const short8*)&Al[w * 32 + lr][lk];
        short8 a1h = *(const short8*)&Ah[w * 32 + 16 + lr][lk];
        short8 a1l = *(const short8*)&Al[w * 32 + 16 + lr][lk];
#pragma unroll
        for (int nb = 0; nb < 4; ++nb) {
            short8 bh = *(const short8*)&Bh[nb * 16 + lr][lk];
            short8 bl = *(const short8*)&Bl[nb * 16 + lr][lk];
            acc[0][nb] = __builtin_amdgcn_mfma_f32_16x16x32_bf16(a0h, bh, acc[0][nb], 0, 0, 0);
            acc[0][nb] = __builtin_amdgcn_mfma_f32_16x16x32_bf16(a0l, bh, acc[0][nb], 0, 0, 0);
            acc[0][nb] = __builtin_amdgcn_mfma_f32_16x16x32_bf16(a0h, bl, acc[0][nb], 0, 0, 0);
            acc[1][nb] = __builtin_amdgcn_mfma_f32_16x16x32_bf16(a1h, bh, acc[1][nb], 0, 0, 0);
            acc[1][nb] = __builtin_amdgcn_mfma_f32_16x16x32_bf16(a1l, bh, acc[1][nb], 0, 0, 0);
            acc[1][nb] = __builtin_amdgcn_mfma_f32_16x16x32_bf16(a1h, bl, acc[1][nb], 0, 0, 0);
        }
        __syncthreads();
    }

    // C/D layout (m89-verified): col = lane&15, row = (lane>>4)*4 + reg
#pragma unroll
    for (int mb = 0; mb < 2; ++mb)
#pragma unroll
        for (int nb = 0; nb < 4; ++nb)
#pragma unroll
            for (int r = 0; r < 4; ++r) {
                int gr = row0 + w * 32 + mb * 16 + (l >> 4) * 4 + r;
                int gc = nb * 16 + (l & 15);
                if (gr < N) h1[(size_t)gr * 64 + gc] = f2bf(acc[mb][nb][r]);
            }
}

// ================= agg1 + GEMM2 fused =================
// one wave per node; QUARTER-WAVE edge parallelism: 16 lanes x ushort4 cover
// one 128-B h1 row, so each h1 load instruction gathers 4 edges.
// VMEM instrs/edge: 3 -> 0.66; serial chain per wave 4x shorter.

__global__ __launch_bounds__(256) void k_agg1(const unsigned short* __restrict__ h1,
                                              const int* __restrict__ rowptr,
                                              const int* __restrict__ csr_src,
                                              const float* __restrict__ dinv,
                                              const float* __restrict__ b1,
                                              const float* __restrict__ W2,
                                              float* __restrict__ h2, int N) {
    int wid = threadIdx.x >> 6;
    int lane = threadIdx.x & 63;
    int n = blockIdx.x * 4 + wid;
    if (n >= N) return;
    int qtr = lane >> 4;            // which of 4 edges in a group
    int cb  = (lane & 15) * 4;      // column base (4 cols per lane)

    float w2r[4][8];
#pragma unroll
    for (int j = 0; j < 4; ++j)
#pragma unroll
        for (int c = 0; c < 8; ++c) w2r[j][c] = W2[(cb + j) * 8 + c];
    float4 bias = *(const float4*)(b1 + cb);
    float dn = dinv[n];
    ushort4 sv = *(const ushort4*)&h1[(size_t)n * 64 + cb];

    int start = __builtin_amdgcn_readfirstlane(rowptr[n]);
    int cnt   = __builtin_amdgcn_readfirstlane(rowptr[n + 1]) - start;
    const int* qp = csr_src + start;

    float ax = 0.f, ay = 0.f, az = 0.f, aw = 0.f;
    int i = 0;
    for (; i + 16 <= cnt; i += 16) {
        int q0 = qp[i      + qtr];
        int q1 = qp[i + 4  + qtr];
        int q2 = qp[i + 8  + qtr];
        int q3 = qp[i + 12 + qtr];
        float w0 = dinv[q0], w1 = dinv[q1], w2 = dinv[q2], w3 = dinv[q3];
        ushort4 v0 = *(const ushort4*)&h1[(size_t)q0 * 64 + cb];
        ushort4 v1 = *(const ushort4*)&h1[(size_t)q1 * 64 + cb];
        ushort4 v2 = *(const ushort4*)&h1[(size_t)q2 * 64 + cb];
        ushort4 v3 = *(const ushort4*)&h1[(size_t)q3 * 64 + cb];
        ax = fmaf(w0, bf2f(v0.x), ax); ay = fmaf(w0, bf2f(v0.y), ay);
        az = fmaf(w0, bf2f(v0.z), az); aw = fmaf(w0, bf2f(v0.w), aw);
        ax = fmaf(w1, bf2f(v1.x), ax); ay = fmaf(w1, bf2f(v1.y), ay);
        az = fmaf(w1, bf2f(v1.z), az); aw = fmaf(w1, bf2f(v1.w), aw);
        ax = fmaf(w2, bf2f(v2.x), ax); ay = fmaf(w2, bf2f(v2.y), ay);
        az = fmaf(w2, bf2f(v2.z), az); aw = fmaf(w2, bf2f(v2.w), aw);
        ax = fmaf(w3, bf2f(v3.x), ax); ay = fmaf(w3, bf2f(v3.y), ay);
        az = fmaf(w3, bf2f(v3.z), az); aw = fmaf(w3, bf2f(v3.w), aw);
    }
    if (i + 8 <= cnt) {
        int q0 = qp[i + qtr];
        int q1 = qp[i + 4 + qtr];
        float w0 = dinv[q0], w1 = dinv[q1];
        ushort4 v0 = *(const ushort4*)&h1[(size_t)q0 * 64 + cb];
        ushort4 v1 = *(const ushort4*)&h1[(size_t)q1 * 64 + cb];
        ax = fmaf(w0, bf2f(v0.x), ax); ay = fmaf(w0, bf2f(v0.y), ay);
        az = fmaf(w0, bf2f(v0.z), az); aw = fmaf(w0, bf2f(v0.w), aw);
        ax = fmaf(w1, bf2f(v1.x), ax); ay = fmaf(w1, bf2f(v1.y), ay);
        az = fmaf(w1, bf2f(v1.z), az); aw = fmaf(w1, bf2f(v1.w), aw);
        i += 8;
    }
    if (i + 4 <= cnt) {
        int q0 = qp[i + qtr];
        float w0 = dinv[q0];
        ushort4 v0 = *(const ushort4*)&h1[(size_t)q0 * 64 + cb];
        ax = fmaf(w0, bf2f(v0.x), ax); ay = fmaf(w0, bf2f(v0.y), ay);
        az = fmaf(w0, bf2f(v0.z), az); aw = fmaf(w0, bf2f(v0.w), aw);
        i += 4;
    }
    int rem = cnt - i;   // 0..3
    if (qtr < rem) {
        int q0 = qp[i + qtr];
        float w0 = dinv[q0];
        ushort4 v0 = *(const ushort4*)&h1[(size_t)q0 * 64 + cb];
        ax = fmaf(w0, bf2f(v0.x), ax); ay = fmaf(w0, bf2f(v0.y), ay);
        az = fmaf(w0, bf2f(v0.z), az); aw = fmaf(w0, bf2f(v0.w), aw);
    }

    // merge the 4 quarter-wave partials (lanes 16 and 32 apart)
    ax += __shfl_xor(ax, 16, 64); ax += __shfl_xor(ax, 32, 64);
    ay += __shfl_xor(ay, 16, 64); ay += __shfl_xor(ay, 32, 64);
    az += __shfl_xor(az, 16, 64); az += __shfl_xor(az, 32, 64);
    aw += __shfl_xor(aw, 16, 64); aw += __shfl_xor(aw, 32, 64);

    float r0 = fmaxf(dn * (ax + dn * bf2f(sv.x)) + bias.x, 0.f);
    float r1 = fmaxf(dn * (ay + dn * bf2f(sv.y)) + bias.y, 0.f);
    float r2 = fmaxf(dn * (az + dn * bf2f(sv.z)) + bias.z, 0.f);
    float r3 = fmaxf(dn * (aw + dn * bf2f(sv.w)) + bias.w, 0.f);

    // fused GEMM2: per output c, partial dot over this lane's 4 cols,
    // then butterfly over the 16-lane group (all groups hold identical sums)
    float keep = 0.f;
#pragma unroll
    for (int c = 0; c < 8; ++c) {
        float s = r0 * w2r[0][c] + r1 * w2r[1][c] + r2 * w2r[2][c] + r3 * w2r[3][c];
        s += __shfl_xor(s, 1, 64);
        s += __shfl_xor(s, 2, 64);
        s += __shfl_xor(s, 4, 64);
        s += __shfl_xor(s, 8, 64);
        keep = ((lane & 7) == c) ? s : keep;
    }
    if (lane < 8) h2[(size_t)n * 8 + lane] = keep;
}

// ================= agg2 =================

__global__ __launch_bounds__(256) void k_agg2(const float* __restrict__ h2,
                                              const int* __restrict__ rowptr,
                                              const int* __restrict__ csr_src,
                                              const float* __restrict__ dinv,
                                              const float* __restrict__ b2,
                                              float* __restrict__ out, int N) {
    int wid = threadIdx.x >> 6;
    int lane = threadIdx.x & 63;
    int n = blockIdx.x * 4 + wid;
    if (n >= N) return;
    int start = rowptr[n];
    int cnt = rowptr[n + 1] - start;
    int c = lane & 7;
    int ii = lane >> 3;

    float a0 = 0.f, a1 = 0.f;
    int i = ii;
    for (; i + 8 < cnt; i += 16) {
        int q0 = csr_src[start + i];
        int q1 = csr_src[start + i + 8];
        float w0 = dinv[q0], w1 = dinv[q1];
        float v0 = h2[(size_t)q0 * 8 + c];
        float v1 = h2[(size_t)q1 * 8 + c];
        a0 = fmaf(w0, v0, a0);
        a1 = fmaf(w1, v1, a1);
    }
    if (i < cnt) {
        int q = csr_src[start + i];
        a0 = fmaf(dinv[q], h2[(size_t)q * 8 + c], a0);
    }
    float acc = a0 + a1;
    acc += __shfl_xor(acc, 8, 64);
    acc += __shfl_xor(acc, 16, 64);
    acc += __shfl_xor(acc, 32, 64);

    if (lane < 8) {
        float dn = dinv[n];
        out[(size_t)n * 8 + lane] =
            dn * (acc + dn * h2[(size_t)n * 8 + lane]) + b2[lane];
    }
}

// ================= host launcher =================

extern "C" void kernel_launch(void* const* d_in, const int* in_sizes, int n_in,
                              void* d_out, int out_size, void* d_ws, size_t ws_size,
                              hipStream_t stream) {
    const float* x  = (const float*)d_in[0];
    const int*   ei = (const int*)d_in[1];
    const float* W1 = (const float*)d_in[2];
    const float* b1 = (const float*)d_in[3];
    const float* W2 = (const float*)d_in[4];
    const float* b2 = (const float*)d_in[5];
    float* out = (float*)d_out;

    const int H   = in_sizes[3];            // 64
    const int FIN = in_sizes[2] / H;        // 512
    const int N   = in_sizes[0] / FIN;      // 100000
    const int E   = in_sizes[1] / 2;        // 3200000
    const int* srcA = ei;
    const int* dstA = ei + E;

    const int B    = (N + NODE_RANGE - 1) >> NODE_SHIFT;   // 782
    const int nCnt = (E + CHUNK - 1) / CHUNK;              // 196

    char* ws = (char*)d_ws;
    size_t off = 0;
    auto alloc = [&](size_t bytes) -> void* {
        void* p = ws + off;
        off += (bytes + 255) & ~(size_t)255;
        return p;
    };
    int*      bucket_cnt   = (int*)alloc((size_t)B * 4);
    int*      bucket_start = (int*)alloc((size_t)(B + 1) * 4);
    int*      blk_base     = (int*)alloc((size_t)nCnt * B * 4);
    unsigned* bucket_pk    = (unsigned*)alloc((size_t)E * 4);
    int*      csr_src      = (int*)alloc((size_t)E * 4);
    int*      rowptr       = (int*)alloc((size_t)(N + 1) * 4);
    float*    dinv         = (float*)alloc((size_t)N * 4);
    unsigned short* h1     = (unsigned short*)alloc((size_t)N * 64 * 2);
    float*    h2           = (float*)alloc((size_t)N * 8 * 4);
    (void)ws_size; (void)n_in; (void)out_size;

    k_zero    <<<(B + 255) / 256, 256, 0, stream>>>(bucket_cnt, B);
    k_bcount  <<<nCnt, 256, 0, stream>>>(dstA, bucket_cnt, blk_base, E, B);
    k_bscan   <<<1, 1024, 0, stream>>>(bucket_cnt, bucket_start, rowptr, B, N);
    k_bscatter<<<nCnt, 256, 0, stream>>>(srcA, dstA, bucket_start, blk_base,
                                         bucket_pk, E, B);
    k_bfinal  <<<B, 256, 0, stream>>>(bucket_pk, bucket_start, rowptr, dinv,
                                      csr_src, N);
    k_gemm1   <<<(N + 127) / 128, 256, 0, stream>>>(x, W1, h1, N);
    k_agg1    <<<(N + 3) / 4, 256, 0, stream>>>(h1, rowptr, csr_src, dinv, b1, W2, h2, N);
    k_agg2    <<<(N + 3) / 4, 256, 0, stream>>>(h2, rowptr, csr_src, dinv, b2, out, N);
}

// Round 2
// 551.958 us; speedup vs baseline: 1.1887x; 1.1887x over previous
//
#include <hip/hip_runtime.h>
#include <cstdint>
#include <cstddef>

// ================= bucket-sort CSR build =================
// Buckets of 128 consecutive node ids. Bucket order == node order, so
// bucket_start doubles as the CSR region start and rowptr is
// bucket_start[b] + local exclusive scan. All per-node atomics are LDS-only.
// Bucket edges are packed: src in bits [0,25), local dst in bits [25,32).

#define NODE_SHIFT 7
#define NODE_RANGE 128
#define MAX_B 1024           // supports N <= 131072 (and N < 2^25 for packing)
#define CHUNK 16384          // edges per bcount/bscatter block (64/thread)

typedef short short8 __attribute__((ext_vector_type(8)));
typedef float f32x4 __attribute__((ext_vector_type(4)));

__device__ __forceinline__ unsigned short f2bf(float f) {
    unsigned u = __float_as_uint(f);
    u += 0x7FFFu + ((u >> 16) & 1u);       // round-to-nearest-even
    return (unsigned short)(u >> 16);
}
__device__ __forceinline__ float bf2f(unsigned short h) {
    return __uint_as_float((unsigned)h << 16);
}

__global__ void k_zero(int* __restrict__ p, int n) {
    int i = blockIdx.x * blockDim.x + threadIdx.x;
    if (i < n) p[i] = 0;
}

// per-chunk LDS histogram over buckets; reserve global per-(block,bin) bases
__global__ __launch_bounds__(256) void k_bcount(const int* __restrict__ dst,
                                                int* __restrict__ bucket_cnt,
                                                int* __restrict__ blk_base,
                                                int E, int B) {
    __shared__ int hist[MAX_B];
    int t = threadIdx.x;
    for (int i = t; i < B; i += 256) hist[i] = 0;
    __syncthreads();
    int base = blockIdx.x * CHUNK;
#pragma unroll 8
    for (int j = 0; j < CHUNK / 256; ++j) {
        int e = base + j * 256 + t;
        if (e < E) atomicAdd(&hist[dst[e] >> NODE_SHIFT], 1);
    }
    __syncthreads();
    for (int i = t; i < B; i += 256)
        blk_base[(size_t)blockIdx.x * B + i] = atomicAdd(&bucket_cnt[i], hist[i]);
}

// single-block exclusive scan of bucket counts -> bucket_start[0..B]
__global__ __launch_bounds__(1024) void k_bscan(const int* __restrict__ bucket_cnt,
                                                int* __restrict__ bucket_start,
                                                int* __restrict__ rowptr,
                                                int B, int N) {
    __shared__ int s[1024];
    int t = threadIdx.x;
    int v = (t < B) ? bucket_cnt[t] : 0;
    s[t] = v;
    __syncthreads();
    for (int off = 1; off < 1024; off <<= 1) {
        int add = (t >= off) ? s[t - off] : 0;
        __syncthreads();
        s[t] += add;
        __syncthreads();
    }
    if (t < B) bucket_start[t] = s[t] - v;
    if (t == 1023) {
        bucket_start[B] = s[1023];   // == E
        rowptr[N] = s[1023];
    }
}

// scatter edges into bucket-grouped order via LDS cursors (no global atomics)
__global__ __launch_bounds__(256) void k_bscatter(const int* __restrict__ src,
                                                  const int* __restrict__ dst,
                                                  const int* __restrict__ bucket_start,
                                                  const int* __restrict__ blk_base,
                                                  unsigned* __restrict__ bucket_pk,
                                                  int E, int B) {
    __shared__ int cur[MAX_B];
    int t = threadIdx.x;
    for (int i = t; i < B; i += 256)
        cur[i] = bucket_start[i] + blk_base[(size_t)blockIdx.x * B + i];
    __syncthreads();
    int base = blockIdx.x * CHUNK;
#pragma unroll 8
    for (int j = 0; j < CHUNK / 256; ++j) {
        int e = base + j * 256 + t;
        if (e < E) {
            int d = dst[e];
            int p = atomicAdd(&cur[d >> NODE_SHIFT], 1);
            bucket_pk[p] = (unsigned)src[e] | ((unsigned)(d & (NODE_RANGE - 1)) << 25);
        }
    }
}

// per-bucket: 128-bin LDS histogram -> rowptr/dinv, then local CSR scatter.
__global__ __launch_bounds__(256) void k_bfinal(const unsigned* __restrict__ bucket_pk,
                                                const int* __restrict__ bucket_start,
                                                int* __restrict__ rowptr,
                                                float* __restrict__ dinv,
                                                int* __restrict__ csr_src,
                                                int N) {
    __shared__ int hist[NODE_RANGE];
    __shared__ int sc[NODE_RANGE];
    int t = threadIdx.x;
    int node0 = blockIdx.x * NODE_RANGE;
    int nn = min(NODE_RANGE, N - node0);
    int estart = bucket_start[blockIdx.x];
    int eend   = bucket_start[blockIdx.x + 1];

    if (t < NODE_RANGE) hist[t] = 0;
    __syncthreads();
    for (int e = estart + t; e < eend; e += 256)
        atomicAdd(&hist[bucket_pk[e] >> 25], 1);
    __syncthreads();

    int v = 0;
    if (t < NODE_RANGE) { v = hist[t]; sc[t] = v; }
    __syncthreads();
    for (int off = 1; off < NODE_RANGE; off <<= 1) {
        int add = (t < NODE_RANGE && t >= off) ? sc[t - off] : 0;
        __syncthreads();
        if (t < NODE_RANGE) sc[t] += add;
        __syncthreads();
    }

    int excl = (t < NODE_RANGE) ? (sc[t] - v) : 0;
    if (t < NODE_RANGE) hist[t] = estart + excl;     // becomes the cursor
    if (t < nn) {
        rowptr[node0 + t] = estart + excl;
        dinv[node0 + t] = rsqrtf((float)(v + 1));    // +1 = self-loop
    }
    __syncthreads();

    for (int e = estart + t; e < eend; e += 256) {
        unsigned q = bucket_pk[e];
        int slot = atomicAdd(&hist[q >> 25], 1);
        csr_src[slot] = (int)(q & 0x01FFFFFFu);
    }
}

// ================= GEMM1 via MFMA: h1s[N,64] = dinv * (x[N,512] @ W1) =======
// bf16 hi/lo split (3 MFMA terms -> ~f32 precision), f32 accumulate.
// Output rows PRE-SCALED by dinv[row] so the aggregation inner loop needs no
// per-edge dinv gather (one dependent-load level removed from agg1/agg2).

__global__ __launch_bounds__(256) void k_gemm1(const float* __restrict__ x,
                                               const float* __restrict__ W1,
                                               const float* __restrict__ dinv,
                                               unsigned short* __restrict__ h1s,
                                               int N) {
    __shared__ unsigned short Ah[128][40];
    __shared__ unsigned short Al[128][40];
    __shared__ unsigned short Bh[64][40];
    __shared__ unsigned short Bl[64][40];

    int t = threadIdx.x;
    int w = t >> 6;
    int l = t & 63;
    int row0 = blockIdx.x * 128;
    int lr = l & 15;            // fragment row (A) / col (B)
    int lk = (l >> 4) * 8;      // fragment k offset

    f32x4 acc[2][4];
#pragma unroll
    for (int mb = 0; mb < 2; ++mb)
#pragma unroll
        for (int nb = 0; nb < 4; ++nb)
            acc[mb][nb] = (f32x4){0.f, 0.f, 0.f, 0.f};

    for (int k0 = 0; k0 < 512; k0 += 32) {
        // ---- stage A tile: 128 rows x 32 k, 4 float4 per thread, coalesced
#pragma unroll
        for (int j = 0; j < 4; ++j) {
            int idx = t + j * 256;          // 0..1023 float4 slots
            int r   = idx >> 3;             // 0..127
            int c4  = idx & 7;              // float4 within 32 cols
            float4 v = {0.f, 0.f, 0.f, 0.f};
            int gr = row0 + r;
            if (gr < N) v = *(const float4*)(x + (size_t)gr * 512 + k0 + c4 * 4);
            ushort4 hi, lo;
            hi.x = f2bf(v.x); lo.x = f2bf(v.x - bf2f(hi.x));
            hi.y = f2bf(v.y); lo.y = f2bf(v.y - bf2f(hi.y));
            hi.z = f2bf(v.z); lo.z = f2bf(v.z - bf2f(hi.z));
            hi.w = f2bf(v.w); lo.w = f2bf(v.w - bf2f(hi.w));
            *(ushort4*)&Ah[r][c4 * 4] = hi;
            *(ushort4*)&Al[r][c4 * 4] = lo;
        }
        // ---- stage B tile transposed: Bt[n][k], 2 float4 per thread
#pragma unroll
        for (int j = 0; j < 2; ++j) {
            int idx = t + j * 256;          // 0..511 float4 slots
            int kk  = idx >> 4;             // 0..31
            int c4  = idx & 15;             // float4 within 64 cols
            float4 v = *(const float4*)(W1 + (size_t)(k0 + kk) * 64 + c4 * 4);
            unsigned short h, lo2;
            h = f2bf(v.x); lo2 = f2bf(v.x - bf2f(h));
            Bh[c4 * 4 + 0][kk] = h; Bl[c4 * 4 + 0][kk] = lo2;
            h = f2bf(v.y); lo2 = f2bf(v.y - bf2f(h));
            Bh[c4 * 4 + 1][kk] = h; Bl[c4 * 4 + 1][kk] = lo2;
            h = f2bf(v.z); lo2 = f2bf(v.z - bf2f(h));
            Bh[c4 * 4 + 2][kk] = h; Bl[c4 * 4 + 2][kk] = lo2;
            h = f2bf(v.w); lo2 = f2bf(v.w - bf2f(h));
            Bh[c4 * 4 + 3][kk] = h; Bl[c4 * 4 + 3][kk] = lo2;
        }
        __syncthreads();

        short8 a0h = *(const short8*)&Ah[w * 32 + lr][lk];
        short8 a0l = *(const short8*)&Al[w * 32 + lr][lk];
        short8 a1h = *(const short8*)&Ah[w * 32 + 16 + lr][lk];
        short8 a1l = *(const short8*)&Al[w * 32 + 16 + lr][lk];
#pragma unroll
        for (int nb = 0; nb < 4; ++nb) {
            short8 bh = *(const short8*)&Bh[nb * 16 + lr][lk];
            short8 bl = *(const short8*)&Bl[nb * 16 + lr][lk];
            acc[0][nb] = __builtin_amdgcn_mfma_f32_16x16x32_bf16(a0h, bh, acc[0][nb], 0, 0, 0);
            acc[0][nb] = __builtin_amdgcn_mfma_f32_16x16x32_bf16(a0l, bh, acc[0][nb], 0, 0, 0);
            acc[0][nb] = __builtin_amdgcn_mfma_f32_16x16x32_bf16(a0h, bl, acc[0][nb], 0, 0, 0);
            acc[1][nb] = __builtin_amdgcn_mfma_f32_16x16x32_bf16(a1h, bh, acc[1][nb], 0, 0, 0);
            acc[1][nb] = __builtin_amdgcn_mfma_f32_16x16x32_bf16(a1l, bh, acc[1][nb], 0, 0, 0);
            acc[1][nb] = __builtin_amdgcn_mfma_f32_16x16x32_bf16(a1h, bl, acc[1][nb], 0, 0, 0);
        }
        __syncthreads();
    }

    // C/D layout (m89-verified): col = lane&15, row = (lane>>4)*4 + reg
    float dscale[2][4];
#pragma unroll
    for (int mb = 0; mb < 2; ++mb)
#pragma unroll
        for (int r = 0; r < 4; ++r) {
            int gr = row0 + w * 32 + mb * 16 + (l >> 4) * 4 + r;
            dscale[mb][r] = (gr < N) ? dinv[gr] : 0.f;
        }
#pragma unroll
    for (int mb = 0; mb < 2; ++mb)
#pragma unroll
        for (int nb = 0; nb < 4; ++nb)
#pragma unroll
            for (int r = 0; r < 4; ++r) {
                int gr = row0 + w * 32 + mb * 16 + (l >> 4) * 4 + r;
                int gc = nb * 16 + (l & 15);
                if (gr < N)
                    h1s[(size_t)gr * 64 + gc] = f2bf(acc[mb][nb][r] * dscale[mb][r]);
            }
}

// ================= agg1 + GEMM2 fused =================
// One wave per node, lane = column (H=64). h1s rows are pre-scaled by
// dinv[src], so the edge loop is: scalar idx load -> uniform-base row gather
// -> add. Two dependent load levels (was three), 16 rows in flight.

__global__ __launch_bounds__(256) void k_agg1(const unsigned short* __restrict__ h1s,
                                              const int* __restrict__ rowptr,
                                              const int* __restrict__ csr_src,
                                              const float* __restrict__ dinv,
                                              const float* __restrict__ b1,
                                              const float* __restrict__ W2,
                                              float* __restrict__ h2s, int N) {
    int wid = threadIdx.x >> 6;
    int lane = threadIdx.x & 63;
    int n = blockIdx.x * 4 + wid;
    if (n >= N) return;

    float4 w2a = *(const float4*)(W2 + lane * 8);
    float4 w2b = *(const float4*)(W2 + lane * 8 + 4);
    float bias = b1[lane];
    float dn   = dinv[n];
    float self = bf2f(h1s[(size_t)n * 64 + lane]);   // already dinv[n]-scaled

    int start = __builtin_amdgcn_readfirstlane(rowptr[n]);
    int cnt   = __builtin_amdgcn_readfirstlane(rowptr[n + 1]) - start;
    const int* qp = csr_src + start;

    float acc0 = 0.f, acc1 = 0.f, acc2 = 0.f, acc3 = 0.f;
    int i = 0;
    for (; i + 16 <= cnt; i += 16) {
        int q[16];
#pragma unroll
        for (int j = 0; j < 16; ++j)
            q[j] = __builtin_amdgcn_readfirstlane(qp[i + j]);
        float v[16];
#pragma unroll
        for (int j = 0; j < 16; ++j)
            v[j] = bf2f(h1s[(size_t)q[j] * 64 + lane]);
        acc0 += v[0] + v[4] + v[8]  + v[12];
        acc1 += v[1] + v[5] + v[9]  + v[13];
        acc2 += v[2] + v[6] + v[10] + v[14];
        acc3 += v[3] + v[7] + v[11] + v[15];
    }
    for (; i + 4 <= cnt; i += 4) {
        int q0 = __builtin_amdgcn_readfirstlane(qp[i + 0]);
        int q1 = __builtin_amdgcn_readfirstlane(qp[i + 1]);
        int q2 = __builtin_amdgcn_readfirstlane(qp[i + 2]);
        int q3 = __builtin_amdgcn_readfirstlane(qp[i + 3]);
        acc0 += bf2f(h1s[(size_t)q0 * 64 + lane]);
        acc1 += bf2f(h1s[(size_t)q1 * 64 + lane]);
        acc2 += bf2f(h1s[(size_t)q2 * 64 + lane]);
        acc3 += bf2f(h1s[(size_t)q3 * 64 + lane]);
    }
    for (; i < cnt; ++i) {
        int q = __builtin_amdgcn_readfirstlane(qp[i]);
        acc0 += bf2f(h1s[(size_t)q * 64 + lane]);
    }

    float r = fmaxf(dn * ((acc0 + acc1) + (acc2 + acc3) + self) + bias, 0.f);

    // fused GEMM2: 8 wave-wide butterfly reductions; output pre-scaled by dn
    float keep = 0.f;
#pragma unroll
    for (int c = 0; c < 8; ++c) {
        float wc = (c < 4) ? ((c == 0) ? w2a.x : (c == 1) ? w2a.y : (c == 2) ? w2a.z : w2a.w)
                           : ((c == 4) ? w2b.x : (c == 5) ? w2b.y : (c == 6) ? w2b.z : w2b.w);
        float s = r * wc;
#pragma unroll
        for (int k = 1; k < 64; k <<= 1) s += __shfl_xor(s, k, 64);
        keep = ((lane & 7) == c) ? s : keep;
    }
    if (lane < 8) h2s[(size_t)n * 8 + lane] = dn * keep;
}

// ================= agg2 =================
// h2s rows pre-scaled by dinv[src]: inner loop is idx load -> gather -> add.

__global__ __launch_bounds__(256) void k_agg2(const float* __restrict__ h2s,
                                              const int* __restrict__ rowptr,
                                              const int* __restrict__ csr_src,
                                              const float* __restrict__ dinv,
                                              const float* __restrict__ b2,
                                              float* __restrict__ out, int N) {
    int wid = threadIdx.x >> 6;
    int lane = threadIdx.x & 63;
    int n = blockIdx.x * 4 + wid;
    if (n >= N) return;
    int start = rowptr[n];
    int cnt = rowptr[n + 1] - start;
    int c = lane & 7;
    int ii = lane >> 3;

    float a0 = 0.f, a1 = 0.f, a2 = 0.f, a3 = 0.f;
    int i = ii;
    for (; i + 24 < cnt; i += 32) {
        int q0 = csr_src[start + i];
        int q1 = csr_src[start + i + 8];
        int q2 = csr_src[start + i + 16];
        int q3 = csr_src[start + i + 24];
        a0 += h2s[(size_t)q0 * 8 + c];
        a1 += h2s[(size_t)q1 * 8 + c];
        a2 += h2s[(size_t)q2 * 8 + c];
        a3 += h2s[(size_t)q3 * 8 + c];
    }
    for (; i < cnt; i += 8) {
        int q = csr_src[start + i];
        a0 += h2s[(size_t)q * 8 + c];
    }
    float acc = (a0 + a1) + (a2 + a3);
    acc += __shfl_xor(acc, 8, 64);
    acc += __shfl_xor(acc, 16, 64);
    acc += __shfl_xor(acc, 32, 64);

    if (lane < 8) {
        out[(size_t)n * 8 + lane] =
            dinv[n] * (acc + h2s[(size_t)n * 8 + lane]) + b2[lane];
    }
}

// ================= host launcher =================

extern "C" void kernel_launch(void* const* d_in, const int* in_sizes, int n_in,
                              void* d_out, int out_size, void* d_ws, size_t ws_size,
                              hipStream_t stream) {
    const float* x  = (const float*)d_in[0];
    const int*   ei = (const int*)d_in[1];
    const float* W1 = (const float*)d_in[2];
    const float* b1 = (const float*)d_in[3];
    const float* W2 = (const float*)d_in[4];
    const float* b2 = (const float*)d_in[5];
    float* out = (float*)d_out;

    const int H   = in_sizes[3];            // 64
    const int FIN = in_sizes[2] / H;        // 512
    const int N   = in_sizes[0] / FIN;      // 100000
    const int E   = in_sizes[1] / 2;        // 3200000
    const int* srcA = ei;
    const int* dstA = ei + E;

    const int B    = (N + NODE_RANGE - 1) >> NODE_SHIFT;   // 782
    const int nCnt = (E + CHUNK - 1) / CHUNK;              // 196

    char* ws = (char*)d_ws;
    size_t off = 0;
    auto alloc = [&](size_t bytes) -> void* {
        void* p = ws + off;
        off += (bytes + 255) & ~(size_t)255;
        return p;
    };
    int*      bucket_cnt   = (int*)alloc((size_t)B * 4);
    int*      bucket_start = (int*)alloc((size_t)(B + 1) * 4);
    int*      blk_base     = (int*)alloc((size_t)nCnt * B * 4);
    unsigned* bucket_pk    = (unsigned*)alloc((size_t)E * 4);
    int*      csr_src      = (int*)alloc((size_t)E * 4);
    int*      rowptr       = (int*)alloc((size_t)(N + 1) * 4);
    float*    dinv         = (float*)alloc((size_t)N * 4);
    unsigned short* h1s    = (unsigned short*)alloc((size_t)N * 64 * 2);
    float*    h2s          = (float*)alloc((size_t)N * 8 * 4);
    (void)ws_size; (void)n_in; (void)out_size;

    k_zero    <<<(B + 255) / 256, 256, 0, stream>>>(bucket_cnt, B);
    k_bcount  <<<nCnt, 256, 0, stream>>>(dstA, bucket_cnt, blk_base, E, B);
    k_bscan   <<<1, 1024, 0, stream>>>(bucket_cnt, bucket_start, rowptr, B, N);
    k_bscatter<<<nCnt, 256, 0, stream>>>(srcA, dstA, bucket_start, blk_base,
                                         bucket_pk, E, B);
    k_bfinal  <<<B, 256, 0, stream>>>(bucket_pk, bucket_start, rowptr, dinv,
                                      csr_src, N);
    k_gemm1   <<<(N + 127) / 128, 256, 0, stream>>>(x, W1, dinv, h1s, N);
    k_agg1    <<<(N + 3) / 4, 256, 0, stream>>>(h1s, rowptr, csr_src, dinv, b1, W2, h2s, N);
    k_agg2    <<<(N + 3) / 4, 256, 0, stream>>>(h2s, rowptr, csr_src, dinv, b2, out, N);
}